// Round 1
// baseline (116.315 us; speedup 1.0000x reference)
//
#include <hip/hip_runtime.h>
#include <math.h>

#define FDIM 5
#define H1N 128
#define H2N 32
#define KOBS 8
#define BLOCK 256

__global__ __launch_bounds__(BLOCK, 3) void barriernet_kernel(
    const float* __restrict__ x,         // nB x 5
    const float* __restrict__ meanp,     // 5
    const float* __restrict__ stdp,      // 5
    const float* __restrict__ W1,        // 128 x 5
    const float* __restrict__ b1,        // 128
    const float* __restrict__ W21,       // 32 x 128
    const float* __restrict__ b21,       // 32
    const float* __restrict__ W22,       // 32 x 128
    const float* __restrict__ b22,       // 32
    const float* __restrict__ W31,       // 2 x 32
    const float* __restrict__ b31,       // 2
    const float* __restrict__ W32,       // 2 x 32
    const float* __restrict__ b32,       // 2
    const float* __restrict__ obstacles, // 8 x 3
    float* __restrict__ out,             // nB x 2
    int nB)
{
    // LDS staging. W21/W22 stored column-major, padded to 36 floats per
    // column so each column base = 144 B (16B-aligned for float4 reads) and
    // staging writes stride 4 banks instead of hitting one bank.
    __shared__ __align__(16) float w1b[H1N][8];    // [i][0..4]=W1 row, [5]=b1
    __shared__ __align__(16) float w21c[H1N][36];  // w21c[i][j] = W21[j][i]
    __shared__ __align__(16) float w22c[H1N][36];
    __shared__ __align__(16) float xs[BLOCK * FDIM];
    __shared__ float sb21[H2N], sb22[H2N];
    __shared__ float sW31[2][H2N], sW32[2][H2N];

    const int t  = threadIdx.x;
    const int r0 = blockIdx.x * BLOCK;
    const int r  = r0 + t;

    if (t < H1N) {
        #pragma unroll
        for (int c = 0; c < FDIM; ++c) w1b[t][c] = W1[t * FDIM + c];
        w1b[t][FDIM] = b1[t];
    }
    #pragma unroll
    for (int e = 0; e < (H1N * H2N) / BLOCK; ++e) {   // 16 iters
        int g = t + e * BLOCK;        // linear index into W21 (row-major 32x128)
        int i = g & (H1N - 1);        // column of W21 = row of w21c
        int j = g >> 7;               // row of W21
        w21c[i][j] = W21[g];
        w22c[i][j] = W22[g];
    }
    if (t < H2N) {
        sb21[t]    = b21[t];
        sb22[t]    = b22[t];
        sW31[0][t] = W31[t];
        sW31[1][t] = W31[H2N + t];
        sW32[0][t] = W32[t];
        sW32[1][t] = W32[H2N + t];
    }
    #pragma unroll
    for (int e = 0; e < FDIM; ++e) {  // coalesced row staging
        int idx = t + e * BLOCK;
        if (r0 * FDIM + idx < nB * FDIM) xs[idx] = x[r0 * FDIM + idx];
    }
    __syncthreads();

    if (r >= nB) return;

    float xr[FDIM];
    #pragma unroll
    for (int c = 0; c < FDIM; ++c) xr[c] = xs[t * FDIM + c];

    float a21[H2N], a22[H2N];
    #pragma unroll
    for (int j = 0; j < H2N; ++j) { a21[j] = sb21[j]; a22[j] = sb22[j]; }

    // Fused layer1 + layer2: never materialize h1[128].
    #pragma unroll 2
    for (int i = 0; i < H1N; ++i) {
        const float4 wa = *reinterpret_cast<const float4*>(&w1b[i][0]);
        const float2 wb = *reinterpret_cast<const float2*>(&w1b[i][4]);
        float h = wb.y;                       // b1[i]
        h = fmaf(xr[0], wa.x, h);
        h = fmaf(xr[1], wa.y, h);
        h = fmaf(xr[2], wa.z, h);
        h = fmaf(xr[3], wa.w, h);
        h = fmaf(xr[4], wb.x, h);
        h = fmaxf(h, 0.0f);                   // relu(h1[i])
        const float4* c21 = reinterpret_cast<const float4*>(&w21c[i][0]);
        const float4* c22 = reinterpret_cast<const float4*>(&w22c[i][0]);
        #pragma unroll
        for (int q = 0; q < H2N / 4; ++q) {
            float4 u = c21[q];
            float4 v = c22[q];
            a21[4*q+0] = fmaf(h, u.x, a21[4*q+0]);
            a21[4*q+1] = fmaf(h, u.y, a21[4*q+1]);
            a21[4*q+2] = fmaf(h, u.z, a21[4*q+2]);
            a21[4*q+3] = fmaf(h, u.w, a21[4*q+3]);
            a22[4*q+0] = fmaf(h, v.x, a22[4*q+0]);
            a22[4*q+1] = fmaf(h, v.y, a22[4*q+1]);
            a22[4*q+2] = fmaf(h, v.z, a22[4*q+2]);
            a22[4*q+3] = fmaf(h, v.w, a22[4*q+3]);
        }
    }

    // Heads: x31 = x21 @ W31.T + b31 ; x32 = 4*sigmoid(x22 @ W32.T + b32)
    float x31_0 = 0.f, x31_1 = 0.f, t32_0 = 0.f, t32_1 = 0.f;
    #pragma unroll
    for (int j = 0; j < H2N; ++j) {
        float v21 = fmaxf(a21[j], 0.0f);
        float v22 = fmaxf(a22[j], 0.0f);
        x31_0 = fmaf(v21, sW31[0][j], x31_0);
        x31_1 = fmaf(v21, sW31[1][j], x31_1);
        t32_0 = fmaf(v22, sW32[0][j], t32_0);
        t32_1 = fmaf(v22, sW32[1][j], t32_1);
    }
    x31_0 += b31[0];
    x31_1 += b31[1];
    t32_0 += b32[0];
    t32_1 += b32[1];
    float s0 = 4.0f / (1.0f + expf(-t32_0));
    float s1 = 4.0f / (1.0f + expf(-t32_1));
    float hcoef = s0 * s1;

    // Geometry. NOTE: reference applies the affine TWICE for xo, and the MLP
    // consumes RAW x (not x0).
    float xo[FDIM];
    #pragma unroll
    for (int c = 0; c < FDIM; ++c) {
        float m = meanp[c], s = stdp[c];
        float x0 = fmaf(xr[c], s, m);
        xo[c] = fmaf(x0, s, m);
    }
    float px = xo[0], py = xo[1], th = xo[2], oppx = xo[3], oppy = xo[4];
    float st, ct;
    sincosf(th, &st, &ct);

    float upper =  INFINITY;
    float lower = -INFINITY;
    #pragma unroll
    for (int j = 0; j < KOBS + 1; ++j) {
        float ox, oy, rr;
        if (j < KOBS) {
            ox = obstacles[j * 3 + 0];
            oy = obstacles[j * 3 + 1];
            rr = obstacles[j * 3 + 2];
        } else {
            ox = oppx; oy = oppy; rr = 0.3f;   // AGENT_RADIUS
        }
        float dx = px - ox;
        float dy = py - oy;
        float bar = fmaf(dx, dx, fmaf(dy, dy, -rr * rr));
        float g1  = -2.0f * fmaf(dx, ct, dy * st);
        float hv  = hcoef * bar;
        float safe = (g1 != 0.0f) ? g1 : 1.0f;
        float ratio = hv / safe;
        if (g1 > 0.0f) upper = fminf(upper, ratio);
        if (g1 < 0.0f) lower = fmaxf(lower, ratio);
    }
    float u1 = fminf(fmaxf(-x31_0, lower), upper);   // jnp.clip order
    float u2 = -x31_1;

    float2 o; o.x = u1; o.y = u2;
    *reinterpret_cast<float2*>(&out[2 * r]) = o;
}

extern "C" void kernel_launch(void* const* d_in, const int* in_sizes, int n_in,
                              void* d_out, int out_size, void* d_ws, size_t ws_size,
                              hipStream_t stream) {
    const float* x         = (const float*)d_in[0];
    const float* meanp     = (const float*)d_in[1];
    const float* stdp      = (const float*)d_in[2];
    const float* W1        = (const float*)d_in[3];
    const float* b1        = (const float*)d_in[4];
    const float* W21       = (const float*)d_in[5];
    const float* b21       = (const float*)d_in[6];
    const float* W22       = (const float*)d_in[7];
    const float* b22       = (const float*)d_in[8];
    const float* W31       = (const float*)d_in[9];
    const float* b31       = (const float*)d_in[10];
    const float* W32       = (const float*)d_in[11];
    const float* b32       = (const float*)d_in[12];
    const float* obstacles = (const float*)d_in[13];
    float* out = (float*)d_out;

    int nB = in_sizes[0] / FDIM;
    int grid = (nB + BLOCK - 1) / BLOCK;
    barriernet_kernel<<<grid, BLOCK, 0, stream>>>(
        x, meanp, stdp, W1, b1, W21, b21, W22, b22,
        W31, b31, W32, b32, obstacles, out, nB);
}

// Round 2
// 41.090 us; speedup vs baseline: 2.8307x; 2.8307x over previous
//
#include <hip/hip_runtime.h>
#include <hip/hip_bf16.h>
#include <math.h>

typedef __attribute__((ext_vector_type(8))) short short8v;
typedef __attribute__((ext_vector_type(4))) float f32x4;

#define BLOCK 256
#define WPB   (BLOCK / 64)
#define GRID  2048

__device__ inline unsigned int pk_bf16(float lo, float hi) {
    unsigned int r;
    asm volatile("v_cvt_pk_bf16_f32 %0, %1, %2" : "=v"(r) : "v"(lo), "v"(hi));
    return r;
}

__global__ __launch_bounds__(BLOCK) void bnet_mfma(
    const float* __restrict__ x,
    const float* __restrict__ meanp, const float* __restrict__ stdp,
    const float* __restrict__ W1,  const float* __restrict__ b1,
    const float* __restrict__ W21, const float* __restrict__ b21,
    const float* __restrict__ W22, const float* __restrict__ b22,
    const float* __restrict__ W31, const float* __restrict__ b31,
    const float* __restrict__ W32, const float* __restrict__ b32,
    const float* __restrict__ obstacles,
    float* __restrict__ out, int nB)
{
    // W1 in fragment-friendly order: w1f[ks][j][q][0..4]=w, [5]=bias, pad to 8.
    // Read addr per (ks,j): 4 distinct 32B chunks (q=0..3) -> conflict-free broadcast.
    __shared__ float w1f[4][8][4][8];             // 4 KB
    // B-fragments pre-packed per consuming lane: fragB[arr*8+nt*4+ks][lane][4 u32]
    __shared__ unsigned int fragB[16][64][4];     // 16 KB

    const int t = threadIdx.x;

    if (t < 128) {   // stage W1 (+bias)
        int ks = t >> 5, q = (t >> 3) & 3, j = t & 7;
        float* d = &w1f[ks][j][q][0];
        #pragma unroll
        for (int c = 0; c < 5; ++c) d[c] = W1[t * 5 + c];
        d[5] = b1[t]; d[6] = 0.f; d[7] = 0.f;
    }
    {   // stage W21/W22 as bf16 B-fragments: value(lane,j) = W[(lane&15)+16*nt][8*(lane>>4)+j+32*ks]
        const float4* w21v = (const float4*)W21;
        const float4* w22v = (const float4*)W22;
        #pragma unroll
        for (int e = 0; e < 4; ++e) {             // 1024 float4 per matrix
            int g4   = t + e * 256;
            int unit = g4 >> 5;                   // 32 float4 per 128-wide row
            int h0   = (g4 & 31) << 2;
            int ks   = h0 >> 5;
            int q    = (h0 >> 3) & 3;
            int j0   = h0 & 7;                    // 0 or 4
            int lane = (q << 4) | (unit & 15);
            int nt   = unit >> 4;
            float4 f1 = w21v[g4];
            float4 f2 = w22v[g4];
            unsigned int* dA = &fragB[nt * 4 + ks][lane][j0 >> 1];
            unsigned int* dB = &fragB[8 + nt * 4 + ks][lane][j0 >> 1];
            dA[0] = pk_bf16(f1.x, f1.y); dA[1] = pk_bf16(f1.z, f1.w);
            dB[0] = pk_bf16(f2.x, f2.y); dB[1] = pk_bf16(f2.z, f2.w);
        }
    }
    __syncthreads();

    const int lane = t & 63;
    const int q    = lane >> 4;
    const int r15  = lane & 15;
    const int wid    = blockIdx.x * WPB + (t >> 6);
    const int nwaves = gridDim.x * WPB;

    // B fragments -> registers, once per wave (64 VGPRs), reused for all tiles.
    short8v bfr[16];
    #pragma unroll
    for (int i = 0; i < 16; ++i) bfr[i] = *(const short8v*)&fragB[i][lane][0];

    // Per-lane head weights (unit = r15 and r15+16) and layer-2 biases.
    const float w31_0a = W31[r15],      w31_0b = W31[16 + r15];
    const float w31_1a = W31[32 + r15], w31_1b = W31[48 + r15];
    const float w32_0a = W32[r15],      w32_0b = W32[16 + r15];
    const float w32_1a = W32[32 + r15], w32_1b = W32[48 + r15];
    const float bb21a = b21[r15], bb21b = b21[16 + r15];
    const float bb22a = b22[r15], bb22b = b22[16 + r15];
    const float bias31_0 = b31[0], bias31_1 = b31[1];
    const float bias32_0 = b32[0], bias32_1 = b32[1];

    // xo = (x*std+mean)*std+mean = x*std^2 + (mean*std+mean)
    float s2[5], ms[5];
    #pragma unroll
    for (int c = 0; c < 5; ++c) { float m = meanp[c], s = stdp[c]; s2[c] = s * s; ms[c] = fmaf(m, s, m); }

    const int ntiles = nB >> 4;
    for (int tile = wid; tile < ntiles; tile += nwaves) {
        const int base = tile << 4;

        // x row for this lane's row (r15); q-groups load redundantly (broadcast-cached)
        float xr[5];
        {
            const float* xp = x + (size_t)(base + r15) * 5;
            #pragma unroll
            for (int c = 0; c < 5; ++c) xr[c] = xp[c];
        }

        // ---- layer 1 directly into A-fragment layout ----
        short8v af[4];
        #pragma unroll
        for (int ks = 0; ks < 4; ++ks) {
            float h[8];
            #pragma unroll
            for (int j = 0; j < 8; ++j) {
                const float* wp = &w1f[ks][j][q][0];
                float4 wa = *(const float4*)wp;
                float2 wb = *(const float2*)(wp + 4);
                float v = fmaf(xr[4], wb.x, wb.y);   // w4*x4 + bias
                v = fmaf(xr[0], wa.x, v);
                v = fmaf(xr[1], wa.y, v);
                v = fmaf(xr[2], wa.z, v);
                v = fmaf(xr[3], wa.w, v);
                h[j] = fmaxf(v, 0.f);                // relu(h1)
            }
            union { unsigned int u[4]; short8v s; } a;
            a.u[0] = pk_bf16(h[0], h[1]); a.u[1] = pk_bf16(h[2], h[3]);
            a.u[2] = pk_bf16(h[4], h[5]); a.u[3] = pk_bf16(h[6], h[7]);
            af[ks] = a.s;
        }

        // ---- layer 2 via MFMA: D[m=row][n=unit] ----
        f32x4 acc21a = {0.f,0.f,0.f,0.f}, acc21b = {0.f,0.f,0.f,0.f};
        f32x4 acc22a = {0.f,0.f,0.f,0.f}, acc22b = {0.f,0.f,0.f,0.f};
        #pragma unroll
        for (int ks = 0; ks < 4; ++ks) {
            acc21a = __builtin_amdgcn_mfma_f32_16x16x32_bf16(af[ks], bfr[0 * 4 + ks], acc21a, 0, 0, 0);
            acc21b = __builtin_amdgcn_mfma_f32_16x16x32_bf16(af[ks], bfr[1 * 4 + ks], acc21b, 0, 0, 0);
            acc22a = __builtin_amdgcn_mfma_f32_16x16x32_bf16(af[ks], bfr[2 * 4 + ks], acc22a, 0, 0, 0);
            acc22b = __builtin_amdgcn_mfma_f32_16x16x32_bf16(af[ks], bfr[3 * 4 + ks], acc22b, 0, 0, 0);
        }

        // ---- heads: relu, partial dot over this lane's 2 units, reduce over 16 lanes ----
        float p0[4], p1[4], p2[4], p3[4];
        #pragma unroll
        for (int r = 0; r < 4; ++r) {
            float v21a = fmaxf(acc21a[r] + bb21a, 0.f);
            float v21b = fmaxf(acc21b[r] + bb21b, 0.f);
            float v22a = fmaxf(acc22a[r] + bb22a, 0.f);
            float v22b = fmaxf(acc22b[r] + bb22b, 0.f);
            p0[r] = fmaf(v21a, w31_0a, v21b * w31_0b);
            p1[r] = fmaf(v21a, w31_1a, v21b * w31_1b);
            p2[r] = fmaf(v22a, w32_0a, v22b * w32_0b);
            p3[r] = fmaf(v22a, w32_1a, v22b * w32_1b);
        }
        #pragma unroll
        for (int m = 1; m < 16; m <<= 1) {
            #pragma unroll
            for (int r = 0; r < 4; ++r) {
                p0[r] += __shfl_xor(p0[r], m);
                p1[r] += __shfl_xor(p1[r], m);
                p2[r] += __shfl_xor(p2[r], m);
                p3[r] += __shfl_xor(p3[r], m);
            }
        }

        // redistribute: this lane handles local row r15 (row = (q)*4+reg lives in group q=r15>>2, reg=r15&3)
        const int srcLane = (r15 >> 2) << 4;
        const int sel = r15 & 3;
        float x31_0, x31_1, t32_0, t32_1;
        {
            float a0 = __shfl(p0[0], srcLane), a1 = __shfl(p0[1], srcLane);
            float a2 = __shfl(p0[2], srcLane), a3 = __shfl(p0[3], srcLane);
            x31_0 = (sel == 0 ? a0 : sel == 1 ? a1 : sel == 2 ? a2 : a3) + bias31_0;
        }
        {
            float a0 = __shfl(p1[0], srcLane), a1 = __shfl(p1[1], srcLane);
            float a2 = __shfl(p1[2], srcLane), a3 = __shfl(p1[3], srcLane);
            x31_1 = (sel == 0 ? a0 : sel == 1 ? a1 : sel == 2 ? a2 : a3) + bias31_1;
        }
        {
            float a0 = __shfl(p2[0], srcLane), a1 = __shfl(p2[1], srcLane);
            float a2 = __shfl(p2[2], srcLane), a3 = __shfl(p2[3], srcLane);
            t32_0 = (sel == 0 ? a0 : sel == 1 ? a1 : sel == 2 ? a2 : a3) + bias32_0;
        }
        {
            float a0 = __shfl(p3[0], srcLane), a1 = __shfl(p3[1], srcLane);
            float a2 = __shfl(p3[2], srcLane), a3 = __shfl(p3[3], srcLane);
            t32_1 = (sel == 0 ? a0 : sel == 1 ? a1 : sel == 2 ? a2 : a3) + bias32_1;
        }

        // ---- epilogue (per lane, row = base + r15; groups q>0 are redundant) ----
        float s0v = __fdividef(4.f, 1.f + __expf(-t32_0));
        float s1v = __fdividef(4.f, 1.f + __expf(-t32_1));
        float hcoef = s0v * s1v;

        float xo[5];
        #pragma unroll
        for (int c = 0; c < 5; ++c) xo[c] = fmaf(xr[c], s2[c], ms[c]);
        float px = xo[0], py = xo[1], th = xo[2], oppx = xo[3], oppy = xo[4];
        float st, ct;
        __sincosf(th, &st, &ct);

        float upper = INFINITY, lower = -INFINITY;
        #pragma unroll
        for (int jo = 0; jo < 9; ++jo) {
            float ox, oy, rr;
            if (jo < 8) { ox = obstacles[jo * 3]; oy = obstacles[jo * 3 + 1]; rr = obstacles[jo * 3 + 2]; }
            else        { ox = oppx; oy = oppy; rr = 0.3f; }
            float dx = px - ox, dy = py - oy;
            float bar = fmaf(dx, dx, fmaf(dy, dy, -rr * rr));
            float g1  = -2.f * fmaf(dx, ct, dy * st);
            float ratio = __fdividef(hcoef * bar, (g1 != 0.f) ? g1 : 1.f);
            if (g1 > 0.f) upper = fminf(upper, ratio);
            if (g1 < 0.f) lower = fmaxf(lower, ratio);
        }
        float u1 = fminf(fmaxf(-x31_0, lower), upper);
        float u2 = -x31_1;

        if (lane < 16) {
            int row = base + lane;
            if (row < nB) {
                float2 o; o.x = u1; o.y = u2;
                *reinterpret_cast<float2*>(out + 2 * (size_t)row) = o;
            }
        }
    }
}

extern "C" void kernel_launch(void* const* d_in, const int* in_sizes, int n_in,
                              void* d_out, int out_size, void* d_ws, size_t ws_size,
                              hipStream_t stream) {
    const float* x         = (const float*)d_in[0];
    const float* meanp     = (const float*)d_in[1];
    const float* stdp      = (const float*)d_in[2];
    const float* W1        = (const float*)d_in[3];
    const float* b1        = (const float*)d_in[4];
    const float* W21       = (const float*)d_in[5];
    const float* b21       = (const float*)d_in[6];
    const float* W22       = (const float*)d_in[7];
    const float* b22       = (const float*)d_in[8];
    const float* W31       = (const float*)d_in[9];
    const float* b31       = (const float*)d_in[10];
    const float* W32       = (const float*)d_in[11];
    const float* b32       = (const float*)d_in[12];
    const float* obstacles = (const float*)d_in[13];
    float* out = (float*)d_out;

    int nB = in_sizes[0] / 5;
    bnet_mfma<<<GRID, BLOCK, 0, stream>>>(
        x, meanp, stdp, W1, b1, W21, b21, W22, b22,
        W31, b31, W32, b32, obstacles, out, nB);
}

// Round 3
// 27.288 us; speedup vs baseline: 4.2625x; 1.5058x over previous
//
#include <hip/hip_runtime.h>
#include <hip/hip_bf16.h>
#include <math.h>

typedef __attribute__((ext_vector_type(8))) short short8v;
typedef __attribute__((ext_vector_type(4))) float f32x4;

#define BLOCK 256
#define WPB   (BLOCK / 64)
#define GRID  1024

__device__ inline unsigned int pk_bf16(float lo, float hi) {
    unsigned int r;
    asm volatile("v_cvt_pk_bf16_f32 %0, %1, %2" : "=v"(r) : "v"(lo), "v"(hi));
    return r;
}

__global__ __launch_bounds__(BLOCK) void bnet_mfma(
    const float* __restrict__ x,
    const float* __restrict__ meanp, const float* __restrict__ stdp,
    const float* __restrict__ W1,  const float* __restrict__ b1,
    const float* __restrict__ W21, const float* __restrict__ b21,
    const float* __restrict__ W22, const float* __restrict__ b22,
    const float* __restrict__ W31, const float* __restrict__ b31,
    const float* __restrict__ W32, const float* __restrict__ b32,
    const float* __restrict__ obstacles,
    float* __restrict__ out, int nB)
{
    // W1 in fragment-friendly order: w1f[ks][j][q][0..4]=w, [5]=bias, pad to 8.
    // Per (ks,j) the wave reads 4 distinct 32B chunks (q=0..3) -> conflict-free.
    __shared__ float w1f[4][8][4][8];             // 4 KB
    // W21/W22 bf16 fragments, per consuming lane. Value(lane, j) =
    // W[(lane&15) + 16*half][8*(lane>>4) + j + 32*ks]. Works as A-fragment
    // (m = lane&15 = unit) in the swapped MFMA.
    __shared__ unsigned int fragB[16][64][4];     // 16 KB

    const int t = threadIdx.x;

    if (t < 128) {   // stage W1 (+bias)
        int ks = t >> 5, q = (t >> 3) & 3, j = t & 7;
        float* d = &w1f[ks][j][q][0];
        #pragma unroll
        for (int c = 0; c < 5; ++c) d[c] = W1[t * 5 + c];
        d[5] = b1[t]; d[6] = 0.f; d[7] = 0.f;
    }
    {   // stage W21/W22 fragments
        const float4* w21v = (const float4*)W21;
        const float4* w22v = (const float4*)W22;
        #pragma unroll
        for (int e = 0; e < 4; ++e) {             // 1024 float4 per matrix
            int g4   = t + e * 256;
            int unit = g4 >> 5;                   // 32 float4 per 128-wide row
            int h0   = (g4 & 31) << 2;
            int ks   = h0 >> 5;
            int q    = (h0 >> 3) & 3;
            int j0   = h0 & 7;                    // 0 or 4
            int lane = (q << 4) | (unit & 15);
            int nt   = unit >> 4;
            float4 f1 = w21v[g4];
            float4 f2 = w22v[g4];
            unsigned int* dA = &fragB[nt * 4 + ks][lane][j0 >> 1];
            unsigned int* dB = &fragB[8 + nt * 4 + ks][lane][j0 >> 1];
            dA[0] = pk_bf16(f1.x, f1.y); dA[1] = pk_bf16(f1.z, f1.w);
            dB[0] = pk_bf16(f2.x, f2.y); dB[1] = pk_bf16(f2.z, f2.w);
        }
    }
    __syncthreads();

    const int lane = t & 63;
    const int q    = lane >> 4;
    const int r15  = lane & 15;
    const int wid    = blockIdx.x * WPB + (t >> 6);
    const int nwaves = gridDim.x * WPB;

    // W2 fragments -> registers, once per wave (64 VGPRs).
    // bfr[0..3]=W21 units 0-15 (ks 0..3), [4..7]=W21 units 16-31,
    // [8..11]=W22 units 0-15, [12..15]=W22 units 16-31.
    short8v bfr[16];
    #pragma unroll
    for (int i = 0; i < 16; ++i) bfr[i] = *(const short8v*)&fragB[i][lane][0];

    // Per-lane layer-2 biases (units 4q+r and 16+4q+r) and head coefficients.
    float bi21[8], bi22[8];
    float c31_0[8], c31_1[8], c32_0[8], c32_1[8];
    {
        const int o = 4 * q;
        *(float4*)&bi21[0]  = *(const float4*)(b21 + o);
        *(float4*)&bi21[4]  = *(const float4*)(b21 + 16 + o);
        *(float4*)&bi22[0]  = *(const float4*)(b22 + o);
        *(float4*)&bi22[4]  = *(const float4*)(b22 + 16 + o);
        *(float4*)&c31_0[0] = *(const float4*)(W31 + o);
        *(float4*)&c31_0[4] = *(const float4*)(W31 + 16 + o);
        *(float4*)&c31_1[0] = *(const float4*)(W31 + 32 + o);
        *(float4*)&c31_1[4] = *(const float4*)(W31 + 48 + o);
        *(float4*)&c32_0[0] = *(const float4*)(W32 + o);
        *(float4*)&c32_0[4] = *(const float4*)(W32 + 16 + o);
        *(float4*)&c32_1[0] = *(const float4*)(W32 + 32 + o);
        *(float4*)&c32_1[4] = *(const float4*)(W32 + 48 + o);
    }
    const float b31_0 = b31[0], b31_1 = b31[1];
    const float b32_0 = b32[0], b32_1 = b32[1];

    // Per-lane obstacle candidates: lane group q handles j = 3q..3q+2 (j=8 is
    // the opponent, j>8 invalid). Merge via shfl_xor min/max at the end.
    float obx[3], oby[3], obr2[3];
    bool  oppf[3], valf[3];
    #pragma unroll
    for (int c = 0; c < 3; ++c) {
        int j = 3 * q + c;
        valf[c] = (j < 9);
        oppf[c] = (j == 8);
        int jj = (j < 8) ? j : 0;
        obx[c] = obstacles[jj * 3];
        oby[c] = obstacles[jj * 3 + 1];
        float rr = (j == 8) ? 0.3f : obstacles[jj * 3 + 2];
        obr2[c] = rr * rr;
    }

    // xo = (x*std+mean)*std+mean = x*std^2 + (mean*std+mean)
    float s2[5], ms[5];
    #pragma unroll
    for (int c = 0; c < 5; ++c) { float m = meanp[c], s = stdp[c]; s2[c] = s * s; ms[c] = fmaf(m, s, m); }

    const int ntiles = nB >> 4;
    for (int tile = wid; tile < ntiles; tile += nwaves) {
        const int base = tile << 4;

        // x row for this lane's row (r15); the 4 q-groups read the same
        // addresses (broadcast, L1-cached).
        float xr[5];
        {
            const float* xp = x + (size_t)(base + r15) * 5;
            #pragma unroll
            for (int c = 0; c < 5; ++c) xr[c] = xp[c];
        }

        // ---- layer 1 directly into fragment layout: lane holds
        // h1[row=r15][k = 8q + j + 32ks] -> valid as MFMA B-operand. ----
        short8v af[4];
        #pragma unroll
        for (int ks = 0; ks < 4; ++ks) {
            float h[8];
            #pragma unroll
            for (int j = 0; j < 8; ++j) {
                const float* wp = &w1f[ks][j][q][0];
                float4 wa = *(const float4*)wp;
                float2 wb = *(const float2*)(wp + 4);
                float v = fmaf(xr[4], wb.x, wb.y);   // w4*x4 + bias
                v = fmaf(xr[0], wa.x, v);
                v = fmaf(xr[1], wa.y, v);
                v = fmaf(xr[2], wa.z, v);
                v = fmaf(xr[3], wa.w, v);
                h[j] = fmaxf(v, 0.f);                // relu(h1)
            }
            union { unsigned int u[4]; short8v s; } a;
            a.u[0] = pk_bf16(h[0], h[1]); a.u[1] = pk_bf16(h[2], h[3]);
            a.u[2] = pk_bf16(h[4], h[5]); a.u[3] = pk_bf16(h[6], h[7]);
            af[ks] = a.s;
        }

        // ---- layer 2, SWAPPED operands: D[m=unit][n=row]. Lane holds,
        // for batch row r15, units {4q+r} (a) and {16+4q+r} (b).
        // Accumulators initialized with the layer-2 bias. ----
        f32x4 a21a = {bi21[0], bi21[1], bi21[2], bi21[3]};
        f32x4 a21b = {bi21[4], bi21[5], bi21[6], bi21[7]};
        f32x4 a22a = {bi22[0], bi22[1], bi22[2], bi22[3]};
        f32x4 a22b = {bi22[4], bi22[5], bi22[6], bi22[7]};
        #pragma unroll
        for (int ks = 0; ks < 4; ++ks) {
            a21a = __builtin_amdgcn_mfma_f32_16x16x32_bf16(bfr[     ks], af[ks], a21a, 0, 0, 0);
            a21b = __builtin_amdgcn_mfma_f32_16x16x32_bf16(bfr[ 4 + ks], af[ks], a21b, 0, 0, 0);
            a22a = __builtin_amdgcn_mfma_f32_16x16x32_bf16(bfr[ 8 + ks], af[ks], a22a, 0, 0, 0);
            a22b = __builtin_amdgcn_mfma_f32_16x16x32_bf16(bfr[12 + ks], af[ks], a22b, 0, 0, 0);
        }

        // ---- heads: per-lane partial dot over its 8 units, then 2-round
        // shfl_xor reduce across q-groups. Every lane ends with row r15's heads.
        float p0 = 0.f, p1 = 0.f, p2 = 0.f, p3 = 0.f;
        #pragma unroll
        for (int r = 0; r < 4; ++r) {
            float v21a = fmaxf(a21a[r], 0.f);
            float v21b = fmaxf(a21b[r], 0.f);
            float v22a = fmaxf(a22a[r], 0.f);
            float v22b = fmaxf(a22b[r], 0.f);
            p0 = fmaf(v21a, c31_0[r], fmaf(v21b, c31_0[4 + r], p0));
            p1 = fmaf(v21a, c31_1[r], fmaf(v21b, c31_1[4 + r], p1));
            p2 = fmaf(v22a, c32_0[r], fmaf(v22b, c32_0[4 + r], p2));
            p3 = fmaf(v22a, c32_1[r], fmaf(v22b, c32_1[4 + r], p3));
        }
        p0 += __shfl_xor(p0, 16); p0 += __shfl_xor(p0, 32);
        p1 += __shfl_xor(p1, 16); p1 += __shfl_xor(p1, 32);
        p2 += __shfl_xor(p2, 16); p2 += __shfl_xor(p2, 32);
        p3 += __shfl_xor(p3, 16); p3 += __shfl_xor(p3, 32);
        float x31_0 = p0 + b31_0;
        float x31_1 = p1 + b31_1;
        float t32_0 = p2 + b32_0;
        float t32_1 = p3 + b32_1;

        // ---- epilogue, candidates split across q-groups ----
        float s0v = __fdividef(4.f, 1.f + __expf(-t32_0));
        float s1v = __fdividef(4.f, 1.f + __expf(-t32_1));
        float hcoef = s0v * s1v;

        float xo[5];
        #pragma unroll
        for (int c = 0; c < 5; ++c) xo[c] = fmaf(xr[c], s2[c], ms[c]);
        float px = xo[0], py = xo[1], th = xo[2], oppx = xo[3], oppy = xo[4];
        float st, ct;
        __sincosf(th, &st, &ct);

        float upper = INFINITY, lower = -INFINITY;
        #pragma unroll
        for (int c = 0; c < 3; ++c) {
            float ox = oppf[c] ? oppx : obx[c];
            float oy = oppf[c] ? oppy : oby[c];
            float dx = px - ox, dy = py - oy;
            float bar = fmaf(dx, dx, fmaf(dy, dy, -obr2[c]));
            float g1  = -2.f * fmaf(dx, ct, dy * st);
            float ratio = __fdividef(hcoef * bar, (g1 != 0.f) ? g1 : 1.f);
            if (valf[c] && g1 > 0.f) upper = fminf(upper, ratio);
            if (valf[c] && g1 < 0.f) lower = fmaxf(lower, ratio);
        }
        upper = fminf(upper, __shfl_xor(upper, 16));
        upper = fminf(upper, __shfl_xor(upper, 32));
        lower = fmaxf(lower, __shfl_xor(lower, 16));
        lower = fmaxf(lower, __shfl_xor(lower, 32));

        float u1 = fminf(fmaxf(-x31_0, lower), upper);
        float u2 = -x31_1;

        if (lane < 16) {
            int row = base + lane;
            if (row < nB) {
                float2 o; o.x = u1; o.y = u2;
                *reinterpret_cast<float2*>(out + 2 * (size_t)row) = o;
            }
        }
    }
}

extern "C" void kernel_launch(void* const* d_in, const int* in_sizes, int n_in,
                              void* d_out, int out_size, void* d_ws, size_t ws_size,
                              hipStream_t stream) {
    const float* x         = (const float*)d_in[0];
    const float* meanp     = (const float*)d_in[1];
    const float* stdp      = (const float*)d_in[2];
    const float* W1        = (const float*)d_in[3];
    const float* b1        = (const float*)d_in[4];
    const float* W21       = (const float*)d_in[5];
    const float* b21       = (const float*)d_in[6];
    const float* W22       = (const float*)d_in[7];
    const float* b22       = (const float*)d_in[8];
    const float* W31       = (const float*)d_in[9];
    const float* b31       = (const float*)d_in[10];
    const float* W32       = (const float*)d_in[11];
    const float* b32       = (const float*)d_in[12];
    const float* obstacles = (const float*)d_in[13];
    float* out = (float*)d_out;

    int nB = in_sizes[0] / 5;
    bnet_mfma<<<GRID, BLOCK, 0, stream>>>(
        x, meanp, stdp, W1, b1, W21, b21, W22, b22,
        W31, b31, W32, b32, obstacles, out, nB);
}

// Round 4
// 23.752 us; speedup vs baseline: 4.8971x; 1.1489x over previous
//
#include <hip/hip_runtime.h>
#include <hip/hip_bf16.h>
#include <math.h>

typedef __attribute__((ext_vector_type(8))) short short8v;
typedef __attribute__((ext_vector_type(4))) float f32x4;

#define BLOCK 256
#define WPB   (BLOCK / 64)
#define GRID  1024

__device__ inline unsigned int pk_bf16(float lo, float hi) {
    unsigned int r;
    asm("v_cvt_pk_bf16_f32 %0, %1, %2" : "=v"(r) : "v"(lo), "v"(hi));
    return r;
}

__global__ __launch_bounds__(BLOCK) void bnet_mfma(
    const float* __restrict__ x,
    const float* __restrict__ meanp, const float* __restrict__ stdp,
    const float* __restrict__ W1,  const float* __restrict__ b1,
    const float* __restrict__ W21, const float* __restrict__ b21,
    const float* __restrict__ W22, const float* __restrict__ b22,
    const float* __restrict__ W31, const float* __restrict__ b31,
    const float* __restrict__ W32, const float* __restrict__ b32,
    const float* __restrict__ obstacles,
    float* __restrict__ out, int nB)
{
    // Layer-1 A-fragments: w1frag[g][lane][4 u32]. Only q=0 lanes (lane<16)
    // are nonzero: slots k=0..4 = W1[16g+m][k], k=5 = b1[16g+m], k>5 = 0.
    __shared__ __align__(16) unsigned int w1frag[8][64][4];   // 8 KB
    // Layer-2 A-fragments (swapped MFMA), with K-permutation
    // pi(q,j,ks) = 16*(2ks + (j>>2)) + 4q + (j&3) applied on the h-unit axis
    // so layer-1 outputs are already in layer-2 B-fragment order.
    __shared__ __align__(16) unsigned int fragB[16][64][4];   // 16 KB

    const int t = threadIdx.x;

    {   // zero w1frag (lanes >= 16 must be zero)
        uint4 z = {0u, 0u, 0u, 0u};
        int s0 = t, s1 = t + 256;
        *(uint4*)&w1frag[s0 >> 6][s0 & 63][0] = z;
        *(uint4*)&w1frag[s1 >> 6][s1 & 63][0] = z;
    }
    __syncthreads();
    if (t < 128) {   // stage W1 (+bias in k=5 slot), bf16
        int m = t & 15, g = t >> 4;
        int u = 16 * g + m;
        const float* wr = W1 + u * 5;
        unsigned int* d = &w1frag[g][m][0];
        d[0] = pk_bf16(wr[0], wr[1]);
        d[1] = pk_bf16(wr[2], wr[3]);
        d[2] = pk_bf16(wr[4], b1[u]);
        d[3] = 0u;
    }
    {   // stage W21/W22 fragments with pi-permuted K axis.
        // Source element block: uo = row of W2, ui0..ui0+3 consecutive cols.
        // ui = 16g + 4q + r  ->  ks = g>>1, jhalf = g&1, slot j = 4*jhalf + r.
        const float4* w21v = (const float4*)W21;
        const float4* w22v = (const float4*)W22;
        #pragma unroll
        for (int e = 0; e < 4; ++e) {             // 1024 float4 per matrix
            int g4   = t + e * 256;
            int uo   = g4 >> 5;                   // output unit (0..31)
            int h0   = (g4 & 31) << 2;            // ui0
            int ks   = h0 >> 5;
            int jh   = (h0 >> 4) & 1;
            int q    = (h0 >> 2) & 3;
            int lane = (q << 4) | (uo & 15);
            int half = uo >> 4;
            float4 f1 = w21v[g4];
            float4 f2 = w22v[g4];
            unsigned int* dA = &fragB[half * 4 + ks][lane][jh * 2];
            unsigned int* dB = &fragB[8 + half * 4 + ks][lane][jh * 2];
            dA[0] = pk_bf16(f1.x, f1.y); dA[1] = pk_bf16(f1.z, f1.w);
            dB[0] = pk_bf16(f2.x, f2.y); dB[1] = pk_bf16(f2.z, f2.w);
        }
    }
    __syncthreads();

    const int lane = t & 63;
    const int q    = lane >> 4;
    const int r15  = lane & 15;
    const int wid    = blockIdx.x * WPB + (t >> 6);
    const int nwaves = gridDim.x * WPB;

    // Resident fragments: W2 (64 VGPR) + W1 (32 VGPR), loaded once per wave.
    short8v bfr[16];
    #pragma unroll
    for (int i = 0; i < 16; ++i) bfr[i] = *(const short8v*)&fragB[i][lane][0];
    short8v w1f[8];
    #pragma unroll
    for (int g = 0; g < 8; ++g) w1f[g] = *(const short8v*)&w1frag[g][lane][0];

    // Per-lane layer-2 biases (units 4q+r / 16+4q+r) and head coefficients.
    float bi21[8], bi22[8];
    float c31_0[8], c31_1[8], c32_0[8], c32_1[8];
    {
        const int o = 4 * q;
        *(float4*)&bi21[0]  = *(const float4*)(b21 + o);
        *(float4*)&bi21[4]  = *(const float4*)(b21 + 16 + o);
        *(float4*)&bi22[0]  = *(const float4*)(b22 + o);
        *(float4*)&bi22[4]  = *(const float4*)(b22 + 16 + o);
        *(float4*)&c31_0[0] = *(const float4*)(W31 + o);
        *(float4*)&c31_0[4] = *(const float4*)(W31 + 16 + o);
        *(float4*)&c31_1[0] = *(const float4*)(W31 + 32 + o);
        *(float4*)&c31_1[4] = *(const float4*)(W31 + 48 + o);
        *(float4*)&c32_0[0] = *(const float4*)(W32 + o);
        *(float4*)&c32_0[4] = *(const float4*)(W32 + 16 + o);
        *(float4*)&c32_1[0] = *(const float4*)(W32 + 32 + o);
        *(float4*)&c32_1[4] = *(const float4*)(W32 + 48 + o);
    }
    const float b31_0 = b31[0], b31_1 = b31[1];
    const float b32_0 = b32[0], b32_1 = b32[1];

    // Obstacle candidates split across q-groups: group q gets j = 3q..3q+2
    // (j==8 is the opponent, j>8 inert). Merged by shfl min/max at the end.
    float obx[3], oby[3], obr2[3];
    bool  oppf[3], valf[3];
    #pragma unroll
    for (int c = 0; c < 3; ++c) {
        int j = 3 * q + c;
        valf[c] = (j < 9);
        oppf[c] = (j == 8);
        int jj = (j < 8) ? j : 0;
        obx[c] = obstacles[jj * 3];
        oby[c] = obstacles[jj * 3 + 1];
        float rr = (j == 8) ? 0.3f : obstacles[jj * 3 + 2];
        obr2[c] = rr * rr;
    }

    // xo = (x*std+mean)*std+mean = x*std^2 + (mean*std+mean)
    float s2[5], ms[5];
    #pragma unroll
    for (int c = 0; c < 5; ++c) { float m = meanp[c], s = stdp[c]; s2[c] = s * s; ms[c] = fmaf(m, s, m); }

    const int ntiles = (nB + 15) >> 4;
    int tile = wid;
    if (tile < ntiles) {
        float xr[5];
        {
            int row = tile * 16 + r15; if (row >= nB) row = nB - 1;
            const float* xp = x + (size_t)row * 5;
            #pragma unroll
            for (int c = 0; c < 5; ++c) xr[c] = xp[c];
        }
        while (true) {
            const int nxt = tile + nwaves;
            const bool has = nxt < ntiles;
            float xn[5];
            if (has) {   // prefetch next tile's x
                int row = nxt * 16 + r15; if (row >= nB) row = nB - 1;
                const float* xp = x + (size_t)row * 5;
                #pragma unroll
                for (int c = 0; c < 5; ++c) xn[c] = xp[c];
            }

            // ---- x B-fragment: q=0 lanes hold k=0..4 = x, k=5 = 1.0 ----
            short8v xfrag;
            {
                float e0 = (q == 0) ? xr[0] : 0.f;
                float e1 = (q == 0) ? xr[1] : 0.f;
                float e2 = (q == 0) ? xr[2] : 0.f;
                float e3 = (q == 0) ? xr[3] : 0.f;
                float e4 = (q == 0) ? xr[4] : 0.f;
                float e5 = (q == 0) ? 1.0f  : 0.f;
                union { unsigned int u[4]; short8v s; } a;
                a.u[0] = pk_bf16(e0, e1);
                a.u[1] = pk_bf16(e2, e3);
                a.u[2] = pk_bf16(e4, e5);
                a.u[3] = 0u;
                xfrag = a.s;
            }

            // ---- layer 1 via MFMA (swapped): D[m=unit16][n=row].
            // Lane holds h-pre units {16g + 4q + r} at row r15. ----
            f32x4 hacc[8];
            #pragma unroll
            for (int g = 0; g < 8; ++g) {
                f32x4 zz = {0.f, 0.f, 0.f, 0.f};
                hacc[g] = __builtin_amdgcn_mfma_f32_16x16x32_bf16(w1f[g], xfrag, zz, 0, 0, 0);
            }

            // relu + pack into layer-2 B-fragments (pi ordering: register-local)
            short8v af[4];
            #pragma unroll
            for (int ks = 0; ks < 4; ++ks) {
                float h0a = fmaxf(hacc[2*ks][0], 0.f),   h1a = fmaxf(hacc[2*ks][1], 0.f);
                float h2a = fmaxf(hacc[2*ks][2], 0.f),   h3a = fmaxf(hacc[2*ks][3], 0.f);
                float h0b = fmaxf(hacc[2*ks+1][0], 0.f), h1b = fmaxf(hacc[2*ks+1][1], 0.f);
                float h2b = fmaxf(hacc[2*ks+1][2], 0.f), h3b = fmaxf(hacc[2*ks+1][3], 0.f);
                union { unsigned int u[4]; short8v s; } a;
                a.u[0] = pk_bf16(h0a, h1a); a.u[1] = pk_bf16(h2a, h3a);
                a.u[2] = pk_bf16(h0b, h1b); a.u[3] = pk_bf16(h2b, h3b);
                af[ks] = a.s;
            }

            // ---- layer 2 (swapped): D[m=unit_out][n=row], bias in acc init ----
            f32x4 a21a = {bi21[0], bi21[1], bi21[2], bi21[3]};
            f32x4 a21b = {bi21[4], bi21[5], bi21[6], bi21[7]};
            f32x4 a22a = {bi22[0], bi22[1], bi22[2], bi22[3]};
            f32x4 a22b = {bi22[4], bi22[5], bi22[6], bi22[7]};
            #pragma unroll
            for (int ks = 0; ks < 4; ++ks) {
                a21a = __builtin_amdgcn_mfma_f32_16x16x32_bf16(bfr[     ks], af[ks], a21a, 0, 0, 0);
                a21b = __builtin_amdgcn_mfma_f32_16x16x32_bf16(bfr[ 4 + ks], af[ks], a21b, 0, 0, 0);
                a22a = __builtin_amdgcn_mfma_f32_16x16x32_bf16(bfr[ 8 + ks], af[ks], a22a, 0, 0, 0);
                a22b = __builtin_amdgcn_mfma_f32_16x16x32_bf16(bfr[12 + ks], af[ks], a22b, 0, 0, 0);
            }

            // ---- heads: per-lane partial dot, 2-round shfl reduce ----
            float p0 = 0.f, p1 = 0.f, p2 = 0.f, p3 = 0.f;
            #pragma unroll
            for (int r = 0; r < 4; ++r) {
                float v21a = fmaxf(a21a[r], 0.f);
                float v21b = fmaxf(a21b[r], 0.f);
                float v22a = fmaxf(a22a[r], 0.f);
                float v22b = fmaxf(a22b[r], 0.f);
                p0 = fmaf(v21a, c31_0[r], fmaf(v21b, c31_0[4 + r], p0));
                p1 = fmaf(v21a, c31_1[r], fmaf(v21b, c31_1[4 + r], p1));
                p2 = fmaf(v22a, c32_0[r], fmaf(v22b, c32_0[4 + r], p2));
                p3 = fmaf(v22a, c32_1[r], fmaf(v22b, c32_1[4 + r], p3));
            }
            p0 += __shfl_xor(p0, 16); p0 += __shfl_xor(p0, 32);
            p1 += __shfl_xor(p1, 16); p1 += __shfl_xor(p1, 32);
            p2 += __shfl_xor(p2, 16); p2 += __shfl_xor(p2, 32);
            p3 += __shfl_xor(p3, 16); p3 += __shfl_xor(p3, 32);
            float x31_0 = p0 + b31_0;
            float x31_1 = p1 + b31_1;
            float t32_0 = p2 + b32_0;
            float t32_1 = p3 + b32_1;

            // ---- epilogue ----
            float s0v = __fdividef(4.f, 1.f + __expf(-t32_0));
            float s1v = __fdividef(4.f, 1.f + __expf(-t32_1));
            float hcoef = s0v * s1v;

            float xo[5];
            #pragma unroll
            for (int c = 0; c < 5; ++c) xo[c] = fmaf(xr[c], s2[c], ms[c]);
            float px = xo[0], py = xo[1], th = xo[2], oppx = xo[3], oppy = xo[4];
            float st, ct;
            __sincosf(th, &st, &ct);

            float upper = INFINITY, lower = -INFINITY;
            #pragma unroll
            for (int c = 0; c < 3; ++c) {
                float ox = oppf[c] ? oppx : obx[c];
                float oy = oppf[c] ? oppy : oby[c];
                float dx = px - ox, dy = py - oy;
                float bar = fmaf(dx, dx, fmaf(dy, dy, -obr2[c]));
                float g1  = -2.f * fmaf(dx, ct, dy * st);
                float ratio = __fdividef(hcoef * bar, (g1 != 0.f) ? g1 : 1.f);
                if (valf[c] && g1 > 0.f) upper = fminf(upper, ratio);
                if (valf[c] && g1 < 0.f) lower = fmaxf(lower, ratio);
            }
            upper = fminf(upper, __shfl_xor(upper, 16));
            upper = fminf(upper, __shfl_xor(upper, 32));
            lower = fmaxf(lower, __shfl_xor(lower, 16));
            lower = fmaxf(lower, __shfl_xor(lower, 32));

            float u1 = fminf(fmaxf(-x31_0, lower), upper);
            float u2 = -x31_1;

            if (lane < 16) {
                int row = tile * 16 + lane;
                if (row < nB) {
                    float2 o; o.x = u1; o.y = u2;
                    *reinterpret_cast<float2*>(out + 2 * (size_t)row) = o;
                }
            }

            if (!has) break;
            tile = nxt;
            #pragma unroll
            for (int c = 0; c < 5; ++c) xr[c] = xn[c];
        }
    }
}

extern "C" void kernel_launch(void* const* d_in, const int* in_sizes, int n_in,
                              void* d_out, int out_size, void* d_ws, size_t ws_size,
                              hipStream_t stream) {
    const float* x         = (const float*)d_in[0];
    const float* meanp     = (const float*)d_in[1];
    const float* stdp      = (const float*)d_in[2];
    const float* W1        = (const float*)d_in[3];
    const float* b1        = (const float*)d_in[4];
    const float* W21       = (const float*)d_in[5];
    const float* b21       = (const float*)d_in[6];
    const float* W22       = (const float*)d_in[7];
    const float* b22       = (const float*)d_in[8];
    const float* W31       = (const float*)d_in[9];
    const float* b31       = (const float*)d_in[10];
    const float* W32       = (const float*)d_in[11];
    const float* b32       = (const float*)d_in[12];
    const float* obstacles = (const float*)d_in[13];
    float* out = (float*)d_out;

    int nB = in_sizes[0] / 5;
    bnet_mfma<<<GRID, BLOCK, 0, stream>>>(
        x, meanp, stdp, W1, b1, W21, b21, W22, b22,
        W31, b31, W32, b32, obstacles, out, nB);
}